// Round 1
// baseline (333.526 us; speedup 1.0000x reference)
//
#include <hip/hip_runtime.h>
#include <math.h>

#define CA_B 16
#define CA_C 16
#define CA_H 256
#define CA_W 256
#define CA_P 48     // perceive channels = 3*C
#define CA_HID 128  // hidden dim

// ---------------------------------------------------------------------------
// Pass 1: perceive (depthwise 3x3, wrap) + MLP (48->128 relu ->16) + stochastic
// update. Writes x_new (all 16 ch) to d_out and x_new alpha (ch 3) to d_ws.
// Block = one image row (256 threads), grid = B*H.
// ---------------------------------------------------------------------------
__global__ __launch_bounds__(256) void nca_update_kernel(
    const float* __restrict__ x, const float* __restrict__ rand_vals,
    const float* __restrict__ w1, const float* __restrict__ b1,
    const float* __restrict__ w2, const float* __restrict__ b2,
    float* __restrict__ xnew, float* __restrict__ alpha_ws)
{
    __shared__ float s_w1[CA_P * CA_HID];  // 24 KB, row-major [48][128]
    __shared__ float s_w2[CA_HID * CA_C];  //  8 KB, row-major [128][16]
    __shared__ float s_b1[CA_HID];
    __shared__ float s_b2[CA_C];

    const int t = threadIdx.x;
    for (int i = t; i < CA_P * CA_HID; i += 256) s_w1[i] = w1[i];
    for (int i = t; i < CA_HID * CA_C; i += 256) s_w2[i] = w2[i];
    if (t < CA_HID) s_b1[t] = b1[t];
    if (t < CA_C)   s_b2[t] = b2[t];
    __syncthreads();

    const int bh = blockIdx.x;
    const int b  = bh >> 8;           // H == 256
    const int h  = bh & (CA_H - 1);
    const int w  = t;
    const int hm = (h + CA_H - 1) & (CA_H - 1);
    const int hp = (h + 1) & (CA_H - 1);
    const int wm = (w + CA_W - 1) & (CA_W - 1);
    const int wp = (w + 1) & (CA_W - 1);

    const size_t img = (size_t)CA_H * CA_W;
    const float* xb = x + (size_t)b * CA_C * img;

    // perceive: p[3c] = identity, p[3c+1] = sobel-x, p[3c+2] = sobel-y
    // (lax.conv is cross-correlation: no kernel flip)
    float p[CA_P];
    #pragma unroll
    for (int c = 0; c < CA_C; c++) {
        const float* xc = xb + (size_t)c * img;
        const float* r0 = xc + (size_t)hm * CA_W;
        const float* r1 = xc + (size_t)h  * CA_W;
        const float* r2 = xc + (size_t)hp * CA_W;
        float a00 = r0[wm], a01 = r0[w], a02 = r0[wp];
        float a10 = r1[wm], a11 = r1[w], a12 = r1[wp];
        float a20 = r2[wm], a21 = r2[w], a22 = r2[wp];
        p[3*c+0] = a11;
        p[3*c+1] = 0.125f*(a02 - a00) + 0.25f*(a12 - a10) + 0.125f*(a22 - a20);
        p[3*c+2] = 0.125f*(a20 - a00) + 0.25f*(a21 - a01) + 0.125f*(a22 - a02);
    }

    float acc[CA_C];
    #pragma unroll
    for (int c = 0; c < CA_C; c++) acc[c] = s_b2[c];

    // MLP: 4 hidden units at a time -> 4 independent FMA chains over k=0..47
    for (int d = 0; d < CA_HID; d += 4) {
        float s0 = s_b1[d+0], s1 = s_b1[d+1], s2 = s_b1[d+2], s3 = s_b1[d+3];
        #pragma unroll
        for (int k = 0; k < CA_P; k++) {
            const float pk = p[k];
            const float* wr = &s_w1[k * CA_HID + d];  // uniform addr: broadcast
            s0 = fmaf(pk, wr[0], s0);
            s1 = fmaf(pk, wr[1], s1);
            s2 = fmaf(pk, wr[2], s2);
            s3 = fmaf(pk, wr[3], s3);
        }
        s0 = fmaxf(s0, 0.0f); s1 = fmaxf(s1, 0.0f);
        s2 = fmaxf(s2, 0.0f); s3 = fmaxf(s3, 0.0f);
        #pragma unroll
        for (int c = 0; c < CA_C; c++) {
            float a = acc[c];
            a = fmaf(s0, s_w2[(d+0)*CA_C + c], a);
            a = fmaf(s1, s_w2[(d+1)*CA_C + c], a);
            a = fmaf(s2, s_w2[(d+2)*CA_C + c], a);
            a = fmaf(s3, s_w2[(d+3)*CA_C + c], a);
            acc[c] = a;
        }
    }

    const float rv   = rand_vals[(size_t)b * img + (size_t)h * CA_W + w];
    const float mask = (rv < 0.5f) ? 1.0f : 0.0f;

    float* yb = xnew + (size_t)b * CA_C * img + (size_t)h * CA_W + w;
    #pragma unroll
    for (int c = 0; c < CA_C; c++) {
        // x center value is p[3c] (identity filter)
        float v = fmaf(acc[c], mask, p[3*c]);
        yb[(size_t)c * img] = v;
        if (c == 3)
            alpha_ws[(size_t)b * img + (size_t)h * CA_W + w] = v;
    }
}

// ---------------------------------------------------------------------------
// Pass 2: life mask. pre = 3x3 wrap max-pool of x alpha; post = same on
// x_new alpha (from d_ws). out[c] *= (pre>0.1 && post>0.1). Only the thread's
// OWN pixel of d_out is read-modified-written -> no cross-block race.
// ---------------------------------------------------------------------------
__global__ __launch_bounds__(256) void nca_mask_kernel(
    const float* __restrict__ x, const float* __restrict__ alpha_ws,
    float* __restrict__ out)
{
    const int bh = blockIdx.x;
    const int b  = bh >> 8;
    const int h  = bh & (CA_H - 1);
    const int w  = threadIdx.x;
    const int hm = (h + CA_H - 1) & (CA_H - 1);
    const int hp = (h + 1) & (CA_H - 1);
    const int wm = (w + CA_W - 1) & (CA_W - 1);
    const int wp = (w + 1) & (CA_W - 1);

    const size_t img = (size_t)CA_H * CA_W;

    const float* xa = x + ((size_t)b * CA_C + 3) * img;  // alpha channel of x
    const float* r0 = xa + (size_t)hm * CA_W;
    const float* r1 = xa + (size_t)h  * CA_W;
    const float* r2 = xa + (size_t)hp * CA_W;
    float pre = fmaxf(fmaxf(fmaxf(r0[wm], r0[w]), fmaxf(r0[wp], r1[wm])),
                      fmaxf(fmaxf(r1[w],  r1[wp]),
                            fmaxf(fmaxf(r2[wm], r2[w]), r2[wp])));

    const float* na = alpha_ws + (size_t)b * img;
    const float* n0 = na + (size_t)hm * CA_W;
    const float* n1 = na + (size_t)h  * CA_W;
    const float* n2 = na + (size_t)hp * CA_W;
    float post = fmaxf(fmaxf(fmaxf(n0[wm], n0[w]), fmaxf(n0[wp], n1[wm])),
                       fmaxf(fmaxf(n1[w],  n1[wp]),
                             fmaxf(fmaxf(n2[wm], n2[w]), n2[wp])));

    const float life = (pre > 0.1f && post > 0.1f) ? 1.0f : 0.0f;

    float* yb = out + (size_t)b * CA_C * img + (size_t)h * CA_W + w;
    #pragma unroll
    for (int c = 0; c < CA_C; c++) {
        yb[(size_t)c * img] *= life;
    }
}

extern "C" void kernel_launch(void* const* d_in, const int* in_sizes, int n_in,
                              void* d_out, int out_size, void* d_ws, size_t ws_size,
                              hipStream_t stream) {
    const float* x         = (const float*)d_in[0];
    const float* rand_vals = (const float*)d_in[1];
    const float* w1        = (const float*)d_in[2];
    const float* b1        = (const float*)d_in[3];
    const float* w2        = (const float*)d_in[4];
    const float* b2        = (const float*)d_in[5];
    float* out      = (float*)d_out;
    float* alpha_ws = (float*)d_ws;   // needs B*H*W*4 = 4 MB

    const int grid = CA_B * CA_H;     // 4096 blocks, one row each
    nca_update_kernel<<<grid, 256, 0, stream>>>(x, rand_vals, w1, b1, w2, b2,
                                                out, alpha_ws);
    nca_mask_kernel<<<grid, 256, 0, stream>>>(x, alpha_ws, out);
}

// Round 2
// 78.604 us; speedup vs baseline: 4.2431x; 4.2431x over previous
//
#include <hip/hip_runtime.h>
#include <hip/hip_bf16.h>

typedef __attribute__((ext_vector_type(8))) short bf16x8;
typedef __attribute__((ext_vector_type(4))) float f32x4;
typedef __attribute__((ext_vector_type(4))) unsigned int u32x4;

#define NC   16
#define IMG  (256*256)

static __device__ __forceinline__ unsigned short f2bf(float f) {
    __hip_bfloat16 h = __float2bfloat16(f);
    union { __hip_bfloat16 hh; unsigned short u; } cv; cv.hh = h; return cv.u;
}
static __device__ __forceinline__ unsigned int packbf2(float a, float b) {
    return (unsigned int)f2bf(a) | ((unsigned int)f2bf(b) << 16);
}

// ---------------------------------------------------------------------------
// Pass 1: perceive (fp32) -> MFMA MLP (bf16 in / fp32 acc) -> masked update.
// Writes out = x_new * pre_life, alpha_ws = alpha_new (unmasked).
// Block = 256 threads = one row = 256 pixels; 4 waves x 64 pixels.
// LDS union region s_u (160 B/pixel rows):
//   phase A: p staging  [256 pixels][64 bf16 k, padded to 80]
//   phase B (per-wave, aliases own p rows): h bounce [16][136 bf16] @ +0,
//            dx bounce [64][80 B f32 rows] @ +4608   (4608+5120 <= 10240)
// ---------------------------------------------------------------------------
__global__ __launch_bounds__(256, 2) void nca_update_mfma(
    const float* __restrict__ x, const float* __restrict__ rand_vals,
    const float* __restrict__ w1, const float* __restrict__ b1,
    const float* __restrict__ w2, const float* __restrict__ b2,
    float* __restrict__ out, float* __restrict__ alpha_ws)
{
    __shared__ __align__(16) unsigned char  s_u[256*160];     // 40960 B
    __shared__ __align__(16) unsigned short s_w1t[128*72];    // 18432 B  [n][k]
    __shared__ __align__(16) unsigned short s_w2t[16*136];    //  4352 B  [c][k]
    __shared__ float s_b1[128];
    __shared__ float s_b2[16];

    const int t = threadIdx.x;

    // ---- stage weights transposed to k-contiguous bf16 ----
    #pragma unroll
    for (int i = 0; i < 24; i++) {                 // w1 (48x128) -> w1t[n][k]
        int idx = i*256 + t;
        s_w1t[(idx & 127)*72 + (idx >> 7)] = f2bf(w1[(idx >> 7)*128 + (idx & 127)]);
    }
    #pragma unroll
    for (int i = 0; i < 8; i++) {                  // zero-pad k = 48..63
        int idx = i*256 + t;
        s_w1t[(idx >> 4)*72 + 48 + (idx & 15)] = 0;
    }
    #pragma unroll
    for (int i = 0; i < 8; i++) {                  // w2 (128x16) -> w2t[c][k]
        int idx = i*256 + t;
        s_w2t[(idx & 15)*136 + (idx >> 4)] = f2bf(w2[(idx >> 4)*16 + (idx & 15)]);
    }
    if (t < 128) s_b1[t] = b1[t];
    if (t < 16)  s_b2[t] = b2[t];

    // ---- perceive (fp32, wrap) ----
    const int b  = blockIdx.x >> 8;
    const int h  = blockIdx.x & 255;
    const int w  = t;
    const int hm = (h + 255) & 255, hp = (h + 1) & 255;
    const int wm = (w + 255) & 255, wp = (w + 1) & 255;

    const float* xb = x + (size_t)b * NC * IMG;
    float p[48], xc[16], premax = 0.0f;
    #pragma unroll
    for (int c = 0; c < 16; c++) {
        const float* xcp = xb + c * IMG;
        const float* r0 = xcp + hm*256;
        const float* r1 = xcp + h *256;
        const float* r2 = xcp + hp*256;
        float a00=r0[wm],a01=r0[w],a02=r0[wp];
        float a10=r1[wm],a11=r1[w],a12=r1[wp];
        float a20=r2[wm],a21=r2[w],a22=r2[wp];
        p[3*c+0]=a11; xc[c]=a11;
        p[3*c+1]=0.125f*(a02-a00)+0.25f*(a12-a10)+0.125f*(a22-a20);
        p[3*c+2]=0.125f*(a20-a00)+0.25f*(a21-a01)+0.125f*(a22-a02);
        if (c == 3)   // fused pre_life pool (alpha channel neighborhood)
            premax = fmaxf(fmaxf(fmaxf(a00,a01),fmaxf(a02,a10)),
                     fmaxf(fmaxf(a11,a12),fmaxf(fmaxf(a20,a21),a22)));
    }
    {   // stage p -> bf16 LDS row (k = 0..47 data, 48..63 zeros), 160 B stride
        unsigned int pk[24];
        #pragma unroll
        for (int j = 0; j < 24; j++) pk[j] = packbf2(p[2*j], p[2*j+1]);
        u32x4* pv = (u32x4*)(s_u + t*160);
        #pragma unroll
        for (int j = 0; j < 6; j++) {
            u32x4 v = {pk[4*j], pk[4*j+1], pk[4*j+2], pk[4*j+3]};
            pv[j] = v;
        }
        u32x4 z = {0,0,0,0};
        pv[6] = z; pv[7] = z;
    }
    __syncthreads();

    // ---- GEMM phase (per wave: 64 pixels) ----
    const int wv = t >> 6, l15 = t & 15, lg = (t >> 4) & 3;
    unsigned char* wavebase = s_u + wv*10240;

    bf16x8 A1[4][2], B1[8][2], B2[4];
    #pragma unroll
    for (int mt = 0; mt < 4; mt++)
        #pragma unroll
        for (int kt = 0; kt < 2; kt++)
            A1[mt][kt] = *(const bf16x8*)(wavebase + (mt*16 + l15)*160 + kt*64 + lg*16);
    #pragma unroll
    for (int nt = 0; nt < 8; nt++)
        #pragma unroll
        for (int kt = 0; kt < 2; kt++)
            B1[nt][kt] = *(const bf16x8*)((const unsigned char*)s_w1t + (nt*16 + l15)*144 + kt*64 + lg*16);
    #pragma unroll
    for (int kt = 0; kt < 4; kt++)
        B2[kt] = *(const bf16x8*)((const unsigned char*)s_w2t + l15*272 + kt*64 + lg*16);
    float b1v[8];
    #pragma unroll
    for (int nt = 0; nt < 8; nt++) b1v[nt] = s_b1[nt*16 + l15];
    const float b2v = s_b2[l15];

    // all p-fragment reads must land before h writes overwrite the region (WAR)
    asm volatile("s_waitcnt lgkmcnt(0)" ::: "memory");
    __builtin_amdgcn_sched_barrier(0);

    #pragma unroll
    for (int mt = 0; mt < 4; mt++) {
        // GEMM1: h[16 pix][128] for this m-tile
        f32x4 hacc[8];
        #pragma unroll
        for (int nt = 0; nt < 8; nt++) {
            f32x4 a = {0.f,0.f,0.f,0.f};
            a = __builtin_amdgcn_mfma_f32_16x16x32_bf16(A1[mt][0], B1[nt][0], a, 0,0,0);
            a = __builtin_amdgcn_mfma_f32_16x16x32_bf16(A1[mt][1], B1[nt][1], a, 0,0,0);
            hacc[nt] = a;
        }
        // bias + relu + bf16, bounce to LDS [row 0..15][n 0..127], 272 B stride
        #pragma unroll
        for (int nt = 0; nt < 8; nt++)
            #pragma unroll
            for (int r = 0; r < 4; r++) {
                float hv = fmaxf(hacc[nt][r] + b1v[nt], 0.0f);
                *(short*)(wavebase + (lg*4 + r)*272 + (nt*16 + l15)*2) = (short)f2bf(hv);
            }
        asm volatile("s_waitcnt lgkmcnt(0)" ::: "memory");   // RAW: h write->read
        __builtin_amdgcn_sched_barrier(0);
        // GEMM2: dx[16 pix][16 c]
        f32x4 acc2 = {0.f,0.f,0.f,0.f};
        #pragma unroll
        for (int kt = 0; kt < 4; kt++) {
            bf16x8 A2 = *(const bf16x8*)(wavebase + l15*272 + kt*64 + lg*16);
            acc2 = __builtin_amdgcn_mfma_f32_16x16x32_bf16(A2, B2[kt], acc2, 0,0,0);
        }
        asm volatile("s_waitcnt lgkmcnt(0)" ::: "memory");   // WAR vs next-mt h
        __builtin_amdgcn_sched_barrier(0);
        // dx -> per-pixel layout [pixloc][c], 80 B rows
        #pragma unroll
        for (int r = 0; r < 4; r++)
            *(float*)(wavebase + 4608 + (mt*16 + lg*4 + r)*80 + l15*4) = acc2[r] + b2v;
    }
    asm volatile("s_waitcnt lgkmcnt(0)" ::: "memory");       // RAW: dx write->read
    __builtin_amdgcn_sched_barrier(0);

    // ---- epilogue: each thread = its own pixel ----
    const unsigned char* mydx = s_u + wv*10240 + 4608 + (t & 63)*80;
    float dxv[16];
    *(f32x4*)&dxv[0]  = *(const f32x4*)(mydx +  0);
    *(f32x4*)&dxv[4]  = *(const f32x4*)(mydx + 16);
    *(f32x4*)&dxv[8]  = *(const f32x4*)(mydx + 32);
    *(f32x4*)&dxv[12] = *(const f32x4*)(mydx + 48);

    const float rv = rand_vals[b*IMG + h*256 + w];
    const float fm = (rv < 0.5f) ? 1.0f : 0.0f;
    const float lifep = (premax > 0.1f) ? 1.0f : 0.0f;

    alpha_ws[b*IMG + h*256 + w] = fmaf(dxv[3], fm, xc[3]);   // true alpha_new
    float* ob = out + (size_t)b*NC*IMG + h*256 + w;
    #pragma unroll
    for (int c = 0; c < 16; c++)
        ob[c*IMG] = fmaf(dxv[c], fm, xc[c]) * lifep;         // pre_life applied
}

// ---------------------------------------------------------------------------
// Pass 2: post_life pool over alpha_new; zero the (rare) dead pixels.
// out already carries x_new * pre_life, so writing 0 where post<=0.1 yields
// x_new * (pre & post) for every pixel. No RMW of the 64 MB tensor.
// ---------------------------------------------------------------------------
__global__ __launch_bounds__(256) void nca_postmask(
    const float* __restrict__ alpha_ws, float* __restrict__ out)
{
    const int b  = blockIdx.x >> 8;
    const int h  = blockIdx.x & 255;
    const int w  = threadIdx.x;
    const int hm = (h + 255) & 255, hp = (h + 1) & 255;
    const int wm = (w + 255) & 255, wp = (w + 1) & 255;

    const float* na = alpha_ws + b*IMG;
    const float* n0 = na + hm*256;
    const float* n1 = na + h *256;
    const float* n2 = na + hp*256;
    float post = fmaxf(fmaxf(fmaxf(n0[wm],n0[w]),fmaxf(n0[wp],n1[wm])),
                 fmaxf(fmaxf(n1[w],n1[wp]),fmaxf(fmaxf(n2[wm],n2[w]),n2[wp])));
    if (!(post > 0.1f)) {
        float* ob = out + (size_t)b*NC*IMG + h*256 + w;
        #pragma unroll
        for (int c = 0; c < 16; c++) ob[c*IMG] = 0.0f;
    }
}

extern "C" void kernel_launch(void* const* d_in, const int* in_sizes, int n_in,
                              void* d_out, int out_size, void* d_ws, size_t ws_size,
                              hipStream_t stream) {
    const float* x         = (const float*)d_in[0];
    const float* rand_vals = (const float*)d_in[1];
    const float* w1        = (const float*)d_in[2];
    const float* b1        = (const float*)d_in[3];
    const float* w2        = (const float*)d_in[4];
    const float* b2        = (const float*)d_in[5];
    float* out      = (float*)d_out;
    float* alpha_ws = (float*)d_ws;   // B*H*W*4 = 4 MB

    const int grid = 16 * 256;        // one block per (b, h) row
    nca_update_mfma<<<grid, 256, 0, stream>>>(x, rand_vals, w1, b1, w2, b2,
                                              out, alpha_ws);
    nca_postmask<<<grid, 256, 0, stream>>>(alpha_ws, out);
}

// Round 3
// 62.749 us; speedup vs baseline: 5.3152x; 1.2527x over previous
//
#include <hip/hip_runtime.h>
#include <hip/hip_bf16.h>

typedef __attribute__((ext_vector_type(8))) short bf16x8;
typedef __attribute__((ext_vector_type(4))) short bf16x4;
typedef __attribute__((ext_vector_type(4))) float f32x4;
typedef __attribute__((ext_vector_type(4))) unsigned int u32x4;
typedef __attribute__((ext_vector_type(2))) unsigned int u32x2;

#define NC   16
#define IMG  (256*256)

// LDS layout (bytes). All strides are 16B-aligned and == {4,12,20,28} mod 32
// dwords -> conflict-free b128/b64 access for 64-lane waves.
#define P_OFF   0        // [256 rows][112 B]  p rows: 48 bf16 (+8 pad shorts)
#define W1_OFF  28672    // [128 rows][112 B]  w1t[n][k]: 48 bf16 (+pad)
#define W2_OFF  43008    // [16 rows][272 B]   w2t[c][k]: 128 bf16 (+pad)
#define B1_OFF  47360    // 128 f32
#define B2_OFF  47872    // 16 f32
#define LDS_TOT 47936
// Per-wave bounce (aliases dead p/w1t regions after preload barrier):
//   h  : [16][272 B] = 4352;  dx : [64][80 B] = 5120;  total 9472/wave.
//   4 waves * 9472 = 37888 <= P(28672)+W1(14336) = 43008. W2/B1/B2 stay live.
#define BNC_SZ  9472
#define BNC_DX  4352

static __device__ __forceinline__ unsigned short f2bf(float f) {
    union { __hip_bfloat16 h; unsigned short u; } cv;
    cv.h = __float2bfloat16(f);
    return cv.u;
}
static __device__ __forceinline__ unsigned int packbf2(float a, float b) {
    return (unsigned int)f2bf(a) | ((unsigned int)f2bf(b) << 16);
}
static __device__ __forceinline__ f32x4 mfma_bf16_16x16x16(bf16x4 a, bf16x4 b, f32x4 c) {
#if __has_builtin(__builtin_amdgcn_mfma_f32_16x16x16bf16_1k)
    return __builtin_amdgcn_mfma_f32_16x16x16bf16_1k(a, b, c, 0, 0, 0);
#else
    f32x4 d;
    asm("v_mfma_f32_16x16x16_bf16 %0, %1, %2, %3" : "=v"(d) : "v"(a), "v"(b), "v"(c));
    return d;
#endif
}

// ---------------------------------------------------------------------------
// Pass 1: perceive (fp32) -> swapped-operand MFMA MLP -> masked update.
// Block = 256 threads = one image row; 4 waves x 64 pixels; 3 blocks/CU.
// GEMM1: D1[hidden][pixel] = mfma(A=w1t, B=p)  (K=48 = 32+16, no zero-pad)
// GEMM2: D2[chan][pixel]   = mfma(A=w2t, B=h)  (K=128 = 4x32)
// ---------------------------------------------------------------------------
__global__ __launch_bounds__(256, 3) void nca_update_mfma(
    const float* __restrict__ x, const float* __restrict__ rand_vals,
    const float* __restrict__ w1, const float* __restrict__ b1,
    const float* __restrict__ w2, const float* __restrict__ b2,
    float* __restrict__ out, float* __restrict__ alpha_ws)
{
    __shared__ __align__(16) unsigned char lds[LDS_TOT];
    const int t = threadIdx.x;

    // XCD-bijective swizzle: 4096 wgs = 8 XCDs x 512 contiguous rows each,
    // so h+/-1 halo rows share an XCD L2.
    const int wg = (blockIdx.x & 7) * 512 + (blockIdx.x >> 3);
    const int b  = wg >> 8;
    const int h  = wg & 255;
    const int w  = t;

    // ---- stage weights (bf16, k-contiguous rows) ----
    #pragma unroll
    for (int i = 0; i < 24; i++) {               // w1 (48x128) -> w1t[n][k]
        int idx = i*256 + t;
        int n = idx & 127, k = idx >> 7;
        *(unsigned short*)(lds + W1_OFF + n*112 + k*2) = f2bf(w1[k*128 + n]);
    }
    #pragma unroll
    for (int i = 0; i < 8; i++) {                // w2 (128x16) -> w2t[c][k]
        int idx = i*256 + t;
        int c = idx & 15, k = idx >> 4;
        *(unsigned short*)(lds + W2_OFF + c*272 + k*2) = f2bf(w2[k*16 + c]);
    }
    if (t < 128) *(float*)(lds + B1_OFF + t*4) = b1[t];
    if (t < 16)  *(float*)(lds + B2_OFF + t*4) = b2[t];

    // ---- perceive (fp32, wrap) ----
    const int hm = (h + 255) & 255, hp = (h + 1) & 255;
    const int wm = (w + 255) & 255, wp = (w + 1) & 255;
    const float* xb = x + (size_t)b * NC * IMG;
    float p[48], premax = 0.0f;
    #pragma unroll
    for (int c = 0; c < 16; c++) {
        const float* xcp = xb + c * IMG;
        const float* r0 = xcp + hm*256;
        const float* r1 = xcp + h *256;
        const float* r2 = xcp + hp*256;
        float a00=r0[wm],a01=r0[w],a02=r0[wp];
        float a10=r1[wm],a11=r1[w],a12=r1[wp];
        float a20=r2[wm],a21=r2[w],a22=r2[wp];
        p[3*c+0]=a11;
        p[3*c+1]=0.125f*(a02-a00)+0.25f*(a12-a10)+0.125f*(a22-a20);
        p[3*c+2]=0.125f*(a20-a00)+0.25f*(a21-a01)+0.125f*(a22-a02);
        if (c == 3)
            premax = fmaxf(fmaxf(fmaxf(a00,a01),fmaxf(a02,a10)),
                     fmaxf(fmaxf(a11,a12),fmaxf(fmaxf(a20,a21),a22)));
    }
    {   // stage p row: 48 bf16, 112 B stride (28 dwords == 28 mod 32: clean)
        unsigned int pk[24];
        #pragma unroll
        for (int j = 0; j < 24; j++) pk[j] = packbf2(p[2*j], p[2*j+1]);
        u32x4* pv = (u32x4*)(lds + P_OFF + t*112);
        #pragma unroll
        for (int j = 0; j < 6; j++) {
            u32x4 v = {pk[4*j], pk[4*j+1], pk[4*j+2], pk[4*j+3]};
            pv[j] = v;
        }
    }
    __syncthreads();   // barrier 1: staging complete

    // ---- preload all fragments (p and w1t become dead block-wide after) ----
    const int wv = t >> 6, l15 = t & 15, lg = (t >> 4) & 3;

    bf16x8 A1a[8]; bf16x4 A1b[8];                // w1t rows (hidden-major)
    #pragma unroll
    for (int mt = 0; mt < 8; mt++) {
        const unsigned char* r = lds + W1_OFF + (mt*16 + l15)*112;
        A1a[mt] = *(const bf16x8*)(r + lg*16);
        A1b[mt] = *(const bf16x4*)(r + 64 + lg*8);
    }
    bf16x8 Bpa[4]; bf16x4 Bpb[4];                // p cols (pixel-major)
    #pragma unroll
    for (int pt = 0; pt < 4; pt++) {
        const unsigned char* r = lds + P_OFF + (wv*64 + pt*16 + l15)*112;
        Bpa[pt] = *(const bf16x8*)(r + lg*16);
        Bpb[pt] = *(const bf16x4*)(r + 64 + lg*8);
    }
    bf16x8 A2[4];                                // w2t rows (channel-major)
    #pragma unroll
    for (int kt = 0; kt < 4; kt++)
        A2[kt] = *(const bf16x8*)(lds + W2_OFF + l15*272 + kt*64 + lg*16);
    f32x4 b2frag = *(const f32x4*)(lds + B2_OFF + lg*16);

    asm volatile("s_waitcnt lgkmcnt(0)" ::: "memory");
    __builtin_amdgcn_sched_barrier(0);
    __syncthreads();   // barrier 2: all preloads done; bounce regions now free

    unsigned char* hb  = lds + wv*BNC_SZ;            // h  [16 pix][272 B]
    unsigned char* dxb = lds + wv*BNC_SZ + BNC_DX;   // dx [64 pix][80 B]

    #pragma unroll
    for (int pt = 0; pt < 4; pt++) {
        // GEMM1: h[hidden][pixel-tile], bias preloaded into accumulator
        f32x4 hacc[8];
        #pragma unroll
        for (int mt = 0; mt < 8; mt++) {
            f32x4 a = *(const f32x4*)(lds + B1_OFF + (mt*16 + lg*4)*4);
            a = __builtin_amdgcn_mfma_f32_16x16x32_bf16(A1a[mt], Bpa[pt], a, 0,0,0);
            a = mfma_bf16_16x16x16(A1b[mt], Bpb[pt], a);
            hacc[mt] = a;
        }
        // WAR: previous iteration's Bh reads must retire before h overwrite
        asm volatile("s_waitcnt lgkmcnt(0)" ::: "memory");
        __builtin_amdgcn_sched_barrier(0);
        // relu + pack + vectorized bounce (lane holds 4 consecutive hidden)
        #pragma unroll
        for (int mt = 0; mt < 8; mt++) {
            float h0 = fmaxf(hacc[mt][0], 0.f), h1 = fmaxf(hacc[mt][1], 0.f);
            float h2 = fmaxf(hacc[mt][2], 0.f), h3 = fmaxf(hacc[mt][3], 0.f);
            u32x2 pk2 = {packbf2(h0, h1), packbf2(h2, h3)};
            *(u32x2*)(hb + l15*272 + mt*32 + lg*8) = pk2;
        }
        asm volatile("s_waitcnt lgkmcnt(0)" ::: "memory");   // RAW h
        __builtin_amdgcn_sched_barrier(0);
        // GEMM2: dx[chan][pixel-tile]
        f32x4 acc2 = b2frag;
        #pragma unroll
        for (int kt = 0; kt < 4; kt++) {
            bf16x8 Bh = *(const bf16x8*)(hb + l15*272 + kt*64 + lg*16);
            acc2 = __builtin_amdgcn_mfma_f32_16x16x32_bf16(A2[kt], Bh, acc2, 0,0,0);
        }
        // lane (l15,lg) holds dx[c=4lg+r][pixel=pt*16+l15] -> one b128
        *(f32x4*)(dxb + (pt*16 + l15)*80 + lg*16) = acc2;
    }
    asm volatile("s_waitcnt lgkmcnt(0)" ::: "memory");
    __builtin_amdgcn_sched_barrier(0);

    // ---- epilogue: thread t owns wave-local pixel (t&63) = column w=t ----
    const unsigned char* myd = dxb + (t & 63)*80;
    float dxv[16];
    *(f32x4*)&dxv[0]  = *(const f32x4*)(myd +  0);
    *(f32x4*)&dxv[4]  = *(const f32x4*)(myd + 16);
    *(f32x4*)&dxv[8]  = *(const f32x4*)(myd + 32);
    *(f32x4*)&dxv[12] = *(const f32x4*)(myd + 48);

    const float rv = rand_vals[b*IMG + h*256 + w];
    const float fm = (rv < 0.5f) ? 1.0f : 0.0f;
    const float lifep = (premax > 0.1f) ? 1.0f : 0.0f;

    const float* xctr = xb + h*256 + w;          // re-read centers (L2-hot)
    const float xa = xctr[3*IMG];
    alpha_ws[b*IMG + h*256 + w] = fmaf(dxv[3], fm, xa);

    float* ob = out + (size_t)b*NC*IMG + h*256 + w;
    #pragma unroll
    for (int c = 0; c < 16; c++)
        ob[c*IMG] = fmaf(dxv[c], fm, xctr[c*IMG]) * lifep;
}

// ---------------------------------------------------------------------------
// Pass 2: post_life pool over alpha_new; zero the (rare) dead pixels.
// ---------------------------------------------------------------------------
__global__ __launch_bounds__(256) void nca_postmask(
    const float* __restrict__ alpha_ws, float* __restrict__ out)
{
    const int wg = (blockIdx.x & 7) * 512 + (blockIdx.x >> 3);
    const int b  = wg >> 8;
    const int h  = wg & 255;
    const int w  = threadIdx.x;
    const int hm = (h + 255) & 255, hp = (h + 1) & 255;
    const int wm = (w + 255) & 255, wp = (w + 1) & 255;

    const float* na = alpha_ws + b*IMG;
    const float* n0 = na + hm*256;
    const float* n1 = na + h *256;
    const float* n2 = na + hp*256;
    float post = fmaxf(fmaxf(fmaxf(n0[wm],n0[w]),fmaxf(n0[wp],n1[wm])),
                 fmaxf(fmaxf(n1[w],n1[wp]),fmaxf(fmaxf(n2[wm],n2[w]),n2[wp])));
    if (!(post > 0.1f)) {
        float* ob = out + (size_t)b*NC*IMG + h*256 + w;
        #pragma unroll
        for (int c = 0; c < 16; c++) ob[c*IMG] = 0.0f;
    }
}

extern "C" void kernel_launch(void* const* d_in, const int* in_sizes, int n_in,
                              void* d_out, int out_size, void* d_ws, size_t ws_size,
                              hipStream_t stream) {
    const float* x         = (const float*)d_in[0];
    const float* rand_vals = (const float*)d_in[1];
    const float* w1        = (const float*)d_in[2];
    const float* b1        = (const float*)d_in[3];
    const float* w2        = (const float*)d_in[4];
    const float* b2        = (const float*)d_in[5];
    float* out      = (float*)d_out;
    float* alpha_ws = (float*)d_ws;   // 4 MB

    const int grid = 16 * 256;
    nca_update_mfma<<<grid, 256, 0, stream>>>(x, rand_vals, w1, b1, w2, b2,
                                              out, alpha_ws);
    nca_postmask<<<grid, 256, 0, stream>>>(alpha_ws, out);
}